// Round 8
// baseline (230.728 us; speedup 1.0000x reference)
//
#include <hip/hip_runtime.h>

// Sparsemax over last axis of (16, 2048, 1024) fp32.
// One wave per row, 16 elems/lane in registers, Newton/Michelot from the
// provable bound tau* >= max-1 (support superset {z > max-1} is tiny).
//
// R5/R6 change: ALL cross-lane reductions via DPP (VALU pipe, ~4-8cy/op)
// instead of __shfl_xor (ds_bpermute on the LDS pipe + lgkmcnt waits).
// Canonical gfx9 pattern: row_shr 1/2/4/8 (inclusive scan -> lane 15/31/47/63
// hold row sums) + row_bcast:15 (rows 1,3) + row_bcast:31 (rows 2,3), total
// lands in lane 63, readlane -> wave-uniform SGPR.

typedef float f32x4 __attribute__((ext_vector_type(4)));

constexpr int N      = 1024;
constexpr int ROWS   = 16 * 2048;     // 32768
constexpr int NBLK   = 2048;          // 8 blocks/CU, fully resident
constexpr int NWAVES = NBLK * 4;      // 8192 waves
constexpr int RPW    = ROWS / NWAVES; // 4 rows per wave

template <int CTRL, int RM>
__device__ __forceinline__ float dpp_mov(float oldv, float src) {
    return __int_as_float(__builtin_amdgcn_update_dpp(
        __float_as_int(oldv), __float_as_int(src), CTRL, RM, 0xf, false));
}

// row_shr codes: 0x110+N. Invalid-source lanes keep `oldv`.
__device__ __forceinline__ float wave_max_dpp(float v) {
    v = fmaxf(v, dpp_mov<0x111, 0xf>(v, v));   // row_shr:1
    v = fmaxf(v, dpp_mov<0x112, 0xf>(v, v));   // row_shr:2
    v = fmaxf(v, dpp_mov<0x114, 0xf>(v, v));   // row_shr:4
    v = fmaxf(v, dpp_mov<0x118, 0xf>(v, v));   // row_shr:8
    v = fmaxf(v, dpp_mov<0x142, 0xa>(v, v));   // row_bcast:15 -> rows 1,3
    v = fmaxf(v, dpp_mov<0x143, 0xc>(v, v));   // row_bcast:31 -> rows 2,3
    return __int_as_float(__builtin_amdgcn_readlane(__float_as_int(v), 63));
}

__device__ __forceinline__ float wave_sum_dpp(float v) {
    v += dpp_mov<0x111, 0xf>(0.0f, v);         // invalid lanes contribute 0
    v += dpp_mov<0x112, 0xf>(0.0f, v);
    v += dpp_mov<0x114, 0xf>(0.0f, v);
    v += dpp_mov<0x118, 0xf>(0.0f, v);
    v += dpp_mov<0x142, 0xa>(0.0f, v);         // masked-off rows add 0
    v += dpp_mov<0x143, 0xc>(0.0f, v);
    return __int_as_float(__builtin_amdgcn_readlane(__float_as_int(v), 63));
}

__global__ __launch_bounds__(256, 8) void sparsemax_kernel(const float* __restrict__ x,
                                                           float* __restrict__ out) {
    const int wid  = threadIdx.x >> 6;
    const int lane = threadIdx.x & 63;
    const int wave = (int)blockIdx.x * 4 + wid;

    const f32x4* __restrict__ xv = reinterpret_cast<const f32x4*>(x);
    f32x4* __restrict__ ov       = reinterpret_cast<f32x4*>(out);

    f32x4 buf0[4], buf1[4];
    {
        const long long b0 = (long long)wave * 256 + lane;
        #pragma unroll
        for (int j = 0; j < 4; ++j) buf0[j] = xv[b0 + 64 * j];
    }

    auto process = [&](const f32x4 (&cb)[4], int row) {
        float z[16];
        #pragma unroll
        for (int j = 0; j < 4; ++j) {
            z[4 * j + 0] = cb[j].x; z[4 * j + 1] = cb[j].y;
            z[4 * j + 2] = cb[j].z; z[4 * j + 3] = cb[j].w;
        }

        // Per-lane max tree (fuses to v_max3), then DPP wave max.
        float m;
        {
            float a0 = fmaxf(z[0], z[1]),  a1 = fmaxf(z[2], z[3]);
            float a2 = fmaxf(z[4], z[5]),  a3 = fmaxf(z[6], z[7]);
            float a4 = fmaxf(z[8], z[9]),  a5 = fmaxf(z[10], z[11]);
            float a6 = fmaxf(z[12], z[13]), a7 = fmaxf(z[14], z[15]);
            float b0m = fmaxf(a0, a1), b1m = fmaxf(a2, a3);
            float b2m = fmaxf(a4, a5), b3m = fmaxf(a6, a7);
            m = fmaxf(fmaxf(b0m, b1m), fmaxf(b2m, b3m));
        }
        m = wave_max_dpp(m);

        // Michelot/Newton from tau0 = max-1 (provable lower bound on tau*).
        // Active sets nested & shrinking; equal cardinality => exact fixed point.
        float tau   = m - 1.0f;
        int   kprev = N + 1;
        for (;;) {
            float s[16];
            int   lc = 0;
            #pragma unroll
            for (int i = 0; i < 16; ++i) {
                const bool p = z[i] > tau;
                s[i] = p ? z[i] : 0.0f;
                lc += (int)__builtin_popcountll(__ballot(p));  // SALU side channel
            }
            float t0 = (s[0] + s[1]) + (s[2] + s[3]);
            float t1 = (s[4] + s[5]) + (s[6] + s[7]);
            float t2 = (s[8] + s[9]) + (s[10] + s[11]);
            float t3 = (s[12] + s[13]) + (s[14] + s[15]);
            float ls = wave_sum_dpp((t0 + t1) + (t2 + t3));
            if (lc >= kprev) break;                 // set stable -> tau exact
            kprev = lc;
            tau = (ls - 1.0f) * __builtin_amdgcn_rcpf((float)lc);
        }

        // Non-temporal stores (pure output stream).
        const long long ob = (long long)row * 256 + lane;
        #pragma unroll
        for (int j = 0; j < 4; ++j) {
            f32x4 o4;
            o4.x = fmaxf(z[4 * j + 0] - tau, 0.f);
            o4.y = fmaxf(z[4 * j + 1] - tau, 0.f);
            o4.z = fmaxf(z[4 * j + 2] - tau, 0.f);
            o4.w = fmaxf(z[4 * j + 3] - tau, 0.f);
            __builtin_nontemporal_store(o4, &ov[ob + 64 * j]);
        }
    };

    #pragma unroll
    for (int t = 0; t < RPW; ++t) {
        // Issue next row's loads into the other buffer; memory-clobber pins
        // them above the compute so they can't be sunk below it.
        if (t + 1 < RPW) {
            const long long nb = (long long)(wave + (t + 1) * NWAVES) * 256 + lane;
            if ((t & 1) == 0) {
                #pragma unroll
                for (int j = 0; j < 4; ++j) buf1[j] = xv[nb + 64 * j];
            } else {
                #pragma unroll
                for (int j = 0; j < 4; ++j) buf0[j] = xv[nb + 64 * j];
            }
            asm volatile("" ::: "memory");
        }
        if ((t & 1) == 0) process(buf0, wave + t * NWAVES);
        else              process(buf1, wave + t * NWAVES);
    }
}

extern "C" void kernel_launch(void* const* d_in, const int* in_sizes, int n_in,
                              void* d_out, int out_size, void* d_ws, size_t ws_size,
                              hipStream_t stream) {
    const float* x   = (const float*)d_in[0];
    float*       out = (float*)d_out;
    hipLaunchKernelGGL(sparsemax_kernel, dim3(NBLK), dim3(256), 0, stream, x, out);
}